// Round 3
// baseline (1582.519 us; speedup 1.0000x reference)
//
#include <hip/hip_runtime.h>
#include <math.h>

#define N_NODES 100000
#define N_EDGES 1600000
#define IN_DIM 256
#define OUT_DIM 64

__device__ inline void fma4(float4& acc, float s, const float4& w) {
    acc.x = fmaf(s, w.x, acc.x); acc.y = fmaf(s, w.y, acc.y);
    acc.z = fmaf(s, w.z, acc.z); acc.w = fmaf(s, w.w, acc.w);
}

// ---------------- GEMM: x[M,64] = inputs[M,256] @ weight[256,64] ----------------
// Block = 256 threads handles 64 rows: each thread owns 4 rows x 4 cols.
// Full weight (64 KB) staged in LDS; each LDS weight load feeds 4 rows.
__global__ __launch_bounds__(256) void gemm_kernel(const float* __restrict__ inputs,
                                                   const float* __restrict__ weight,
                                                   float* __restrict__ x) {
    __shared__ float w_lds[IN_DIM * OUT_DIM];  // 64 KB
    const int tid = threadIdx.x;

    // Cooperative weight load: 4096 float4, 16 per thread, coalesced.
    const float4* w4 = (const float4*)weight;
    float4* wl4 = (float4*)w_lds;
    #pragma unroll
    for (int i = 0; i < 16; ++i)
        wl4[tid + i * 256] = w4[tid + i * 256];
    __syncthreads();

    const int rbase = blockIdx.x * 64 + (tid >> 4) * 4;  // 4 rows per thread
    const int cg = tid & 15;                              // cols 4*cg..4*cg+3

    // Clamp row pointers for the (only) partial last block; stores are guarded.
    const float4* arow[4];
    #pragma unroll
    for (int r = 0; r < 4; ++r) {
        int row = rbase + r; if (row > N_NODES - 1) row = N_NODES - 1;
        arow[r] = (const float4*)(inputs + (size_t)row * IN_DIM);
    }

    float4 acc[4];
    #pragma unroll
    for (int r = 0; r < 4; ++r) acc[r] = make_float4(0.f, 0.f, 0.f, 0.f);

    #pragma unroll 4
    for (int k4 = 0; k4 < IN_DIM / 4; ++k4) {
        float4 v[4];
        #pragma unroll
        for (int r = 0; r < 4; ++r) v[r] = arow[r][k4];
        const int kb = k4 * 4;
        const float4 w0 = *(const float4*)(w_lds + (kb + 0) * OUT_DIM + cg * 4);
        const float4 w1 = *(const float4*)(w_lds + (kb + 1) * OUT_DIM + cg * 4);
        const float4 w2 = *(const float4*)(w_lds + (kb + 2) * OUT_DIM + cg * 4);
        const float4 w3 = *(const float4*)(w_lds + (kb + 3) * OUT_DIM + cg * 4);
        #pragma unroll
        for (int r = 0; r < 4; ++r) {
            fma4(acc[r], v[r].x, w0);
            fma4(acc[r], v[r].y, w1);
            fma4(acc[r], v[r].z, w2);
            fma4(acc[r], v[r].w, w3);
        }
    }

    #pragma unroll
    for (int r = 0; r < 4; ++r) {
        const int row = rbase + r;
        if (row < N_NODES)
            *(float4*)(x + (size_t)row * OUT_DIM + cg * 4) = acc[r];
    }
}

// ---------------- Scatter: agg[rows[e]] += x[cols[e]] ----------------
// edge_index is int32 on device (R2's int64 read crashed with OOB fault).
// 16 threads/edge, float4 gather from x, 4 HW fp32 atomics into agg.
__global__ __launch_bounds__(256) void scatter_kernel(const int* __restrict__ rows,
                                                      const int* __restrict__ cols,
                                                      const float* __restrict__ x,
                                                      float* __restrict__ agg) {
    const int gid = blockIdx.x * 256 + threadIdx.x;
    const int e = gid >> 4;
    const int ch = gid & 15;
    if (e >= N_EDGES) return;
    const int r = rows[e];  // same address across 16 lanes -> broadcast
    const int c = cols[e];
    const float4 v = *(const float4*)(x + (size_t)c * OUT_DIM + ch * 4);
    float* dst = agg + (size_t)r * OUT_DIM + ch * 4;
    unsafeAtomicAdd(dst + 0, v.x);
    unsafeAtomicAdd(dst + 1, v.y);
    unsafeAtomicAdd(dst + 2, v.z);
    unsafeAtomicAdd(dst + 3, v.w);
}

// ---------------- Sigmoid in-place on d_out ----------------
__global__ __launch_bounds__(256) void sigmoid_kernel(float* __restrict__ out, int n4) {
    const int i = blockIdx.x * 256 + threadIdx.x;
    if (i >= n4) return;
    float4 v = ((const float4*)out)[i];
    v.x = 1.f / (1.f + __expf(-v.x));
    v.y = 1.f / (1.f + __expf(-v.y));
    v.z = 1.f / (1.f + __expf(-v.z));
    v.w = 1.f / (1.f + __expf(-v.w));
    ((float4*)out)[i] = v;
}

extern "C" void kernel_launch(void* const* d_in, const int* in_sizes, int n_in,
                              void* d_out, int out_size, void* d_ws, size_t ws_size,
                              hipStream_t stream) {
    const float* inputs = (const float*)d_in[0];
    const int* edge_index = (const int*)d_in[1];  // [2, N_EDGES], int32 on device
    const float* weight = (const float*)d_in[2];
    float* out = (float*)d_out;          // agg accumulator, then sigmoid in-place
    float* x = (float*)d_ws;             // projected features, 25.6 MB

    const int* rows = edge_index;
    const int* cols = edge_index + N_EDGES;

    // d_out is poisoned each call -> zero it (capture-legal memset node).
    hipMemsetAsync(d_out, 0, (size_t)out_size * sizeof(float), stream);

    gemm_kernel<<<(N_NODES + 63) / 64, 256, 0, stream>>>(inputs, weight, x);

    const long long scatter_threads = (long long)N_EDGES * 16;
    scatter_kernel<<<(int)((scatter_threads + 255) / 256), 256, 0, stream>>>(rows, cols, x, out);

    const int n4 = N_NODES * OUT_DIM / 4;
    sigmoid_kernel<<<(n4 + 255) / 256, 256, 0, stream>>>(out, n4);
}

// Round 4
// 480.328 us; speedup vs baseline: 3.2947x; 3.2947x over previous
//
#include <hip/hip_runtime.h>
#include <math.h>

#define N_NODES 100000
#define N_EDGES 1600000
#define IN_DIM 256
#define OUT_DIM 64

#define SCAN_CHUNK 2048
#define NBLK ((N_NODES + 1 + SCAN_CHUNK - 1) / SCAN_CHUNK)  // 49

// ---- workspace layout (bytes) ----
#define X_OFF         0UL          // 25,600,000 B: x[N_NODES][64] fp32
#define COUNTS_OFF    25600000UL   // 400,000 B: int counts[N_NODES]
#define OFFSETS_OFF   26000000UL   // 400,004 B: int offsets[N_NODES+1]
#define CURSOR_OFF    26400016UL   // 400,000 B: int cursor[N_NODES]
#define BLOCKSUMS_OFF 26800016UL   // 256 B
#define BLOCKOFFS_OFF 26800272UL   // 256 B
#define SORTED_OFF    26800544UL   // 6,400,000 B: int sorted_cols[N_EDGES]
// total ~33.2 MB

__device__ inline void fma4(float4& acc, float s, const float4& w) {
    acc.x = fmaf(s, w.x, acc.x); acc.y = fmaf(s, w.y, acc.y);
    acc.z = fmaf(s, w.z, acc.z); acc.w = fmaf(s, w.w, acc.w);
}

// ---------------- GEMM: x[M,64] = inputs[M,256] @ weight[256,64] ----------------
// (unchanged from R3 — isolate this round's scatter change)
__global__ __launch_bounds__(256) void gemm_kernel(const float* __restrict__ inputs,
                                                   const float* __restrict__ weight,
                                                   float* __restrict__ x) {
    __shared__ float w_lds[IN_DIM * OUT_DIM];  // 64 KB
    const int tid = threadIdx.x;

    const float4* w4 = (const float4*)weight;
    float4* wl4 = (float4*)w_lds;
    #pragma unroll
    for (int i = 0; i < 16; ++i)
        wl4[tid + i * 256] = w4[tid + i * 256];
    __syncthreads();

    const int rbase = blockIdx.x * 64 + (tid >> 4) * 4;  // 4 rows per thread
    const int cg = tid & 15;                              // cols 4*cg..4*cg+3

    const float4* arow[4];
    #pragma unroll
    for (int r = 0; r < 4; ++r) {
        int row = rbase + r; if (row > N_NODES - 1) row = N_NODES - 1;
        arow[r] = (const float4*)(inputs + (size_t)row * IN_DIM);
    }

    float4 acc[4];
    #pragma unroll
    for (int r = 0; r < 4; ++r) acc[r] = make_float4(0.f, 0.f, 0.f, 0.f);

    #pragma unroll 4
    for (int k4 = 0; k4 < IN_DIM / 4; ++k4) {
        float4 v[4];
        #pragma unroll
        for (int r = 0; r < 4; ++r) v[r] = arow[r][k4];
        const int kb = k4 * 4;
        const float4 w0 = *(const float4*)(w_lds + (kb + 0) * OUT_DIM + cg * 4);
        const float4 w1 = *(const float4*)(w_lds + (kb + 1) * OUT_DIM + cg * 4);
        const float4 w2 = *(const float4*)(w_lds + (kb + 2) * OUT_DIM + cg * 4);
        const float4 w3 = *(const float4*)(w_lds + (kb + 3) * OUT_DIM + cg * 4);
        #pragma unroll
        for (int r = 0; r < 4; ++r) {
            fma4(acc[r], v[r].x, w0);
            fma4(acc[r], v[r].y, w1);
            fma4(acc[r], v[r].z, w2);
            fma4(acc[r], v[r].w, w3);
        }
    }

    #pragma unroll
    for (int r = 0; r < 4; ++r) {
        const int row = rbase + r;
        if (row < N_NODES)
            *(float4*)(x + (size_t)row * OUT_DIM + cg * 4) = acc[r];
    }
}

// ---------------- CSR build step 1: histogram of rows ----------------
__global__ __launch_bounds__(256) void hist_kernel(const int* __restrict__ rows,
                                                   int* __restrict__ counts) {
    const int e = blockIdx.x * 256 + threadIdx.x;
    if (e < N_EDGES) atomicAdd(&counts[rows[e]], 1);
}

// ---------------- CSR step 2a: per-chunk totals ----------------
__global__ __launch_bounds__(256) void scan_reduce(const int* __restrict__ counts,
                                                   int* __restrict__ blocksums) {
    __shared__ int lds[256];
    const int b = blockIdx.x, t = threadIdx.x;
    const int base = b * SCAN_CHUNK + t * 8;
    int s = 0;
    #pragma unroll
    for (int i = 0; i < 8; ++i) {
        const int idx = base + i;
        s += (idx < N_NODES) ? counts[idx] : 0;
    }
    lds[t] = s; __syncthreads();
    for (int off = 128; off > 0; off >>= 1) {
        if (t < off) lds[t] += lds[t + off];
        __syncthreads();
    }
    if (t == 0) blocksums[b] = lds[0];
}

// ---------------- CSR step 2b: exclusive scan of chunk totals (1 wave) ----------------
__global__ __launch_bounds__(64) void scan_toplevel(const int* __restrict__ blocksums,
                                                    int* __restrict__ blockoffs) {
    const int t = threadIdx.x;
    const int mine = (t < NBLK) ? blocksums[t] : 0;
    int v = mine;
    #pragma unroll
    for (int d = 1; d < 64; d <<= 1) {
        const int u = __shfl_up(v, d, 64);
        if (t >= d) v += u;
    }
    if (t < NBLK) blockoffs[t] = v - mine;  // exclusive
}

// ---------------- CSR step 2c: full exclusive scan -> offsets, cursor ----------------
__global__ __launch_bounds__(256) void scan_final(const int* __restrict__ counts,
                                                  const int* __restrict__ blockoffs,
                                                  int* __restrict__ offsets,
                                                  int* __restrict__ cursor) {
    __shared__ int a[256], bbuf[256];
    const int b = blockIdx.x, t = threadIdx.x;
    const int base = b * SCAN_CHUNK + t * 8;
    int v[8]; int s = 0;
    #pragma unroll
    for (int i = 0; i < 8; ++i) {
        const int idx = base + i;
        v[i] = (idx < N_NODES) ? counts[idx] : 0;
        s += v[i];
    }
    a[t] = s; __syncthreads();
    int* src = a; int* dst = bbuf;
    for (int off = 1; off < 256; off <<= 1) {
        const int x = src[t] + ((t >= off) ? src[t - off] : 0);
        dst[t] = x; __syncthreads();
        int* tmp = src; src = dst; dst = tmp;
    }
    int run = blockoffs[b] + (src[t] - s);  // exclusive prefix for this thread's first elem
    #pragma unroll
    for (int i = 0; i < 8; ++i) {
        const int idx = base + i;
        if (idx <= N_NODES) {
            offsets[idx] = run;
            if (idx < N_NODES) cursor[idx] = run;
        }
        run += v[i];
    }
}

// ---------------- CSR step 3: permute cols into row-sorted order ----------------
__global__ __launch_bounds__(256) void permute_kernel(const int* __restrict__ rows,
                                                      const int* __restrict__ cols,
                                                      int* __restrict__ cursor,
                                                      int* __restrict__ sorted_cols) {
    const int e = blockIdx.x * 256 + threadIdx.x;
    if (e < N_EDGES) {
        const int r = rows[e];
        const int pos = atomicAdd(&cursor[r], 1);
        sorted_cols[pos] = cols[e];
    }
}

// ---------------- Pull-mode aggregate + fused sigmoid ----------------
// One wave per row; lane = output column. Gathers x[col][lane] (256B coalesced
// per edge) over the row's contiguous CSR segment. No fp32 atomics.
__global__ __launch_bounds__(256) void aggregate_kernel(const int* __restrict__ offsets,
                                                        const int* __restrict__ sorted_cols,
                                                        const float* __restrict__ x,
                                                        float* __restrict__ out) {
    const int row = blockIdx.x * 4 + (threadIdx.x >> 6);
    const int lane = threadIdx.x & 63;
    if (row >= N_NODES) return;
    const int start = offsets[row];
    const int end = offsets[row + 1];
    float acc = 0.f;
    int j = start;
    for (; j + 3 < end; j += 4) {
        const int c0 = sorted_cols[j + 0];
        const int c1 = sorted_cols[j + 1];
        const int c2 = sorted_cols[j + 2];
        const int c3 = sorted_cols[j + 3];
        const float a0 = x[(size_t)c0 * OUT_DIM + lane];
        const float a1 = x[(size_t)c1 * OUT_DIM + lane];
        const float a2 = x[(size_t)c2 * OUT_DIM + lane];
        const float a3 = x[(size_t)c3 * OUT_DIM + lane];
        acc += (a0 + a1) + (a2 + a3);
    }
    for (; j < end; ++j)
        acc += x[(size_t)sorted_cols[j] * OUT_DIM + lane];
    out[(size_t)row * OUT_DIM + lane] = 1.f / (1.f + __expf(-acc));
}

extern "C" void kernel_launch(void* const* d_in, const int* in_sizes, int n_in,
                              void* d_out, int out_size, void* d_ws, size_t ws_size,
                              hipStream_t stream) {
    const float* inputs = (const float*)d_in[0];
    const int* edge_index = (const int*)d_in[1];  // [2, N_EDGES], int32 on device
    const float* weight = (const float*)d_in[2];
    float* out = (float*)d_out;

    char* ws = (char*)d_ws;
    float* x         = (float*)(ws + X_OFF);
    int* counts      = (int*)(ws + COUNTS_OFF);
    int* offsets     = (int*)(ws + OFFSETS_OFF);
    int* cursor      = (int*)(ws + CURSOR_OFF);
    int* blocksums   = (int*)(ws + BLOCKSUMS_OFF);
    int* blockoffs   = (int*)(ws + BLOCKOFFS_OFF);
    int* sorted_cols = (int*)(ws + SORTED_OFF);

    const int* rows = edge_index;
    const int* cols = edge_index + N_EDGES;

    // ws is re-poisoned each call -> zero the histogram counters.
    hipMemsetAsync(counts, 0, N_NODES * sizeof(int), stream);

    gemm_kernel<<<(N_NODES + 63) / 64, 256, 0, stream>>>(inputs, weight, x);

    hist_kernel<<<(N_EDGES + 255) / 256, 256, 0, stream>>>(rows, counts);
    scan_reduce<<<NBLK, 256, 0, stream>>>(counts, blocksums);
    scan_toplevel<<<1, 64, 0, stream>>>(blocksums, blockoffs);
    scan_final<<<NBLK, 256, 0, stream>>>(counts, blockoffs, offsets, cursor);
    permute_kernel<<<(N_EDGES + 255) / 256, 256, 0, stream>>>(rows, cols, cursor, sorted_cols);

    aggregate_kernel<<<(N_NODES + 3) / 4, 256, 0, stream>>>(offsets, sorted_cols, x, out);
}

// Round 5
// 430.693 us; speedup vs baseline: 3.6744x; 1.1152x over previous
//
#include <hip/hip_runtime.h>
#include <math.h>

#define N_NODES 100000
#define N_EDGES 1600000
#define IN_DIM 256
#define OUT_DIM 64

#define SCAN_CHUNK 2048
#define NBLK ((N_NODES + 1 + SCAN_CHUNK - 1) / SCAN_CHUNK)  // 49

#define NPART 8
#define PART_SIZE ((N_NODES + NPART - 1) / NPART)  // 12500 rows per partition

// ---- workspace layout (bytes) ----
#define X_OFF         0UL          // 25,600,000 B: x[N_NODES][64] fp32
#define COUNTS_OFF    25600000UL   // 400,000 B: int counts[N_NODES]
#define OFFSETS_OFF   26000000UL   // 400,004 B: int offsets[N_NODES+1]
#define CURSOR_OFF    26400016UL   // 400,000 B: int cursor[N_NODES]
#define BLOCKSUMS_OFF 26800016UL   // 256 B
#define BLOCKOFFS_OFF 26800272UL   // 256 B
#define SORTED_OFF    26800544UL   // 6,400,000 B: int sorted_cols[N_EDGES]
// total ~33.2 MB

__device__ inline void fma4(float4& acc, float s, const float4& w) {
    acc.x = fmaf(s, w.x, acc.x); acc.y = fmaf(s, w.y, acc.y);
    acc.z = fmaf(s, w.z, acc.z); acc.w = fmaf(s, w.w, acc.w);
}

// ---------------- GEMM: x[M,64] = inputs[M,256] @ weight[256,64] ----------------
__global__ __launch_bounds__(256) void gemm_kernel(const float* __restrict__ inputs,
                                                   const float* __restrict__ weight,
                                                   float* __restrict__ x) {
    __shared__ float w_lds[IN_DIM * OUT_DIM];  // 64 KB
    const int tid = threadIdx.x;

    const float4* w4 = (const float4*)weight;
    float4* wl4 = (float4*)w_lds;
    #pragma unroll
    for (int i = 0; i < 16; ++i)
        wl4[tid + i * 256] = w4[tid + i * 256];
    __syncthreads();

    const int rbase = blockIdx.x * 64 + (tid >> 4) * 4;  // 4 rows per thread
    const int cg = tid & 15;                              // cols 4*cg..4*cg+3

    const float4* arow[4];
    #pragma unroll
    for (int r = 0; r < 4; ++r) {
        int row = rbase + r; if (row > N_NODES - 1) row = N_NODES - 1;
        arow[r] = (const float4*)(inputs + (size_t)row * IN_DIM);
    }

    float4 acc[4];
    #pragma unroll
    for (int r = 0; r < 4; ++r) acc[r] = make_float4(0.f, 0.f, 0.f, 0.f);

    #pragma unroll 4
    for (int k4 = 0; k4 < IN_DIM / 4; ++k4) {
        float4 v[4];
        #pragma unroll
        for (int r = 0; r < 4; ++r) v[r] = arow[r][k4];
        const int kb = k4 * 4;
        const float4 w0 = *(const float4*)(w_lds + (kb + 0) * OUT_DIM + cg * 4);
        const float4 w1 = *(const float4*)(w_lds + (kb + 1) * OUT_DIM + cg * 4);
        const float4 w2 = *(const float4*)(w_lds + (kb + 2) * OUT_DIM + cg * 4);
        const float4 w3 = *(const float4*)(w_lds + (kb + 3) * OUT_DIM + cg * 4);
        #pragma unroll
        for (int r = 0; r < 4; ++r) {
            fma4(acc[r], v[r].x, w0);
            fma4(acc[r], v[r].y, w1);
            fma4(acc[r], v[r].z, w2);
            fma4(acc[r], v[r].w, w3);
        }
    }

    #pragma unroll
    for (int r = 0; r < 4; ++r) {
        const int row = rbase + r;
        if (row < N_NODES)
            *(float4*)(x + (size_t)row * OUT_DIM + cg * 4) = acc[r];
    }
}

// ---------------- CSR build step 1: histogram of rows ----------------
__global__ __launch_bounds__(256) void hist_kernel(const int* __restrict__ rows,
                                                   int* __restrict__ counts) {
    const int e = blockIdx.x * 256 + threadIdx.x;
    if (e < N_EDGES) atomicAdd(&counts[rows[e]], 1);
}

// ---------------- CSR step 2a: per-chunk totals ----------------
__global__ __launch_bounds__(256) void scan_reduce(const int* __restrict__ counts,
                                                   int* __restrict__ blocksums) {
    __shared__ int lds[256];
    const int b = blockIdx.x, t = threadIdx.x;
    const int base = b * SCAN_CHUNK + t * 8;
    int s = 0;
    #pragma unroll
    for (int i = 0; i < 8; ++i) {
        const int idx = base + i;
        s += (idx < N_NODES) ? counts[idx] : 0;
    }
    lds[t] = s; __syncthreads();
    for (int off = 128; off > 0; off >>= 1) {
        if (t < off) lds[t] += lds[t + off];
        __syncthreads();
    }
    if (t == 0) blocksums[b] = lds[0];
}

// ---------------- CSR step 2b: exclusive scan of chunk totals (1 wave) ----------------
__global__ __launch_bounds__(64) void scan_toplevel(const int* __restrict__ blocksums,
                                                    int* __restrict__ blockoffs) {
    const int t = threadIdx.x;
    const int mine = (t < NBLK) ? blocksums[t] : 0;
    int v = mine;
    #pragma unroll
    for (int d = 1; d < 64; d <<= 1) {
        const int u = __shfl_up(v, d, 64);
        if (t >= d) v += u;
    }
    if (t < NBLK) blockoffs[t] = v - mine;  // exclusive
}

// ---------------- CSR step 2c: full exclusive scan -> offsets, cursor ----------------
__global__ __launch_bounds__(256) void scan_final(const int* __restrict__ counts,
                                                  const int* __restrict__ blockoffs,
                                                  int* __restrict__ offsets,
                                                  int* __restrict__ cursor) {
    __shared__ int a[256], bbuf[256];
    const int b = blockIdx.x, t = threadIdx.x;
    const int base = b * SCAN_CHUNK + t * 8;
    int v[8]; int s = 0;
    #pragma unroll
    for (int i = 0; i < 8; ++i) {
        const int idx = base + i;
        v[i] = (idx < N_NODES) ? counts[idx] : 0;
        s += v[i];
    }
    a[t] = s; __syncthreads();
    int* src = a; int* dst = bbuf;
    for (int off = 1; off < 256; off <<= 1) {
        const int x = src[t] + ((t >= off) ? src[t - off] : 0);
        dst[t] = x; __syncthreads();
        int* tmp = src; src = dst; dst = tmp;
    }
    int run = blockoffs[b] + (src[t] - s);  // exclusive prefix for this thread's first elem
    #pragma unroll
    for (int i = 0; i < 8; ++i) {
        const int idx = base + i;
        if (idx <= N_NODES) {
            offsets[idx] = run;
            if (idx < N_NODES) cursor[idx] = run;
        }
        run += v[i];
    }
}

// ---------------- CSR step 3: XCD-partitioned permute ----------------
// blockIdx % 8 selects a row partition; under round-robin block->XCD dispatch
// all writers of partition p sit on XCD p, so its ~800 KB sorted segment stays
// resident in that XCD's 4 MB L2 until fully written (kills the 16x write
// amplification seen in R4: WRITE_SIZE 105 MB for a 6.4 MB array).
// Edges are re-read 8x, but they're L3-resident after hist_kernel.
__global__ __launch_bounds__(256) void permute_kernel(const int* __restrict__ rows,
                                                      const int* __restrict__ cols,
                                                      int* __restrict__ cursor,
                                                      int* __restrict__ sorted_cols) {
    const int part = blockIdx.x & (NPART - 1);
    const int e = (blockIdx.x >> 3) * 256 + threadIdx.x;
    if (e >= N_EDGES) return;
    const int r = rows[e];
    if ((unsigned)(r - part * PART_SIZE) < (unsigned)PART_SIZE) {
        const int pos = atomicAdd(&cursor[r], 1);
        sorted_cols[pos] = cols[e];
    }
}

// ---------------- Pull-mode aggregate + fused sigmoid ----------------
__global__ __launch_bounds__(256) void aggregate_kernel(const int* __restrict__ offsets,
                                                        const int* __restrict__ sorted_cols,
                                                        const float* __restrict__ x,
                                                        float* __restrict__ out) {
    const int row = blockIdx.x * 4 + (threadIdx.x >> 6);
    const int lane = threadIdx.x & 63;
    if (row >= N_NODES) return;
    const int start = offsets[row];
    const int end = offsets[row + 1];
    float acc = 0.f;
    int j = start;
    for (; j + 3 < end; j += 4) {
        const int c0 = sorted_cols[j + 0];
        const int c1 = sorted_cols[j + 1];
        const int c2 = sorted_cols[j + 2];
        const int c3 = sorted_cols[j + 3];
        const float a0 = x[(size_t)c0 * OUT_DIM + lane];
        const float a1 = x[(size_t)c1 * OUT_DIM + lane];
        const float a2 = x[(size_t)c2 * OUT_DIM + lane];
        const float a3 = x[(size_t)c3 * OUT_DIM + lane];
        acc += (a0 + a1) + (a2 + a3);
    }
    for (; j < end; ++j)
        acc += x[(size_t)sorted_cols[j] * OUT_DIM + lane];
    out[(size_t)row * OUT_DIM + lane] = 1.f / (1.f + __expf(-acc));
}

extern "C" void kernel_launch(void* const* d_in, const int* in_sizes, int n_in,
                              void* d_out, int out_size, void* d_ws, size_t ws_size,
                              hipStream_t stream) {
    const float* inputs = (const float*)d_in[0];
    const int* edge_index = (const int*)d_in[1];  // [2, N_EDGES], int32 on device
    const float* weight = (const float*)d_in[2];
    float* out = (float*)d_out;

    char* ws = (char*)d_ws;
    float* x         = (float*)(ws + X_OFF);
    int* counts      = (int*)(ws + COUNTS_OFF);
    int* offsets     = (int*)(ws + OFFSETS_OFF);
    int* cursor      = (int*)(ws + CURSOR_OFF);
    int* blocksums   = (int*)(ws + BLOCKSUMS_OFF);
    int* blockoffs   = (int*)(ws + BLOCKOFFS_OFF);
    int* sorted_cols = (int*)(ws + SORTED_OFF);

    const int* rows = edge_index;
    const int* cols = edge_index + N_EDGES;

    // ws is re-poisoned each call -> zero the histogram counters.
    hipMemsetAsync(counts, 0, N_NODES * sizeof(int), stream);

    gemm_kernel<<<(N_NODES + 63) / 64, 256, 0, stream>>>(inputs, weight, x);

    hist_kernel<<<(N_EDGES + 255) / 256, 256, 0, stream>>>(rows, counts);
    scan_reduce<<<NBLK, 256, 0, stream>>>(counts, blocksums);
    scan_toplevel<<<1, 64, 0, stream>>>(blocksums, blockoffs);
    scan_final<<<NBLK, 256, 0, stream>>>(counts, blockoffs, offsets, cursor);

    const int nchunks = (N_EDGES + 255) / 256;
    permute_kernel<<<nchunks * NPART, 256, 0, stream>>>(rows, cols, cursor, sorted_cols);

    aggregate_kernel<<<(N_NODES + 3) / 4, 256, 0, stream>>>(offsets, sorted_cols, x, out);
}

// Round 7
// 385.264 us; speedup vs baseline: 4.1076x; 1.1179x over previous
//
#include <hip/hip_runtime.h>
#include <math.h>

#define N_NODES 100000
#define N_EDGES 1600000
#define IN_DIM 256
#define OUT_DIM 64

#define SCAN_CHUNK 2048
#define NBLK ((N_NODES + 1 + SCAN_CHUNK - 1) / SCAN_CHUNK)  // 49

#define NPART 8
#define PART_SIZE ((N_NODES + NPART - 1) / NPART)  // 12500 rows per partition

// ---- workspace layout (bytes) ----
#define X_OFF         0UL          // 25,600,000 B: x[N_NODES][64] fp32
#define COUNTS_OFF    25600000UL   // 400,000 B: int counts[N_NODES]
#define OFFSETS_OFF   26000000UL   // 400,004 B: int offsets[N_NODES+1]
#define CURSOR_OFF    26400016UL   // 400,000 B: int cursor[N_NODES]; first 64KB doubles as W-image (stream-ordered: gemm reads it before scan_final writes cursor)
#define BLOCKSUMS_OFF 26800016UL   // 256 B
#define BLOCKOFFS_OFF 26800272UL   // 256 B
#define SORTED_OFF    26800544UL   // 6,400,000 B: int sorted_cols[N_EDGES]
// total ~33.2 MB

typedef short bf16x8 __attribute__((ext_vector_type(8)));
typedef float f32x4 __attribute__((ext_vector_type(4)));

// ---------------- Weight -> bf16 hi/lo B-fragment image (64 KB) ----------------
// Image layout: 64 chunks of 1KB. Chunk c=(t*8+s)*2+h, h=0:hi, 1:lo.
// Within a chunk: lane l's 16B at l*16 = 8 bf16: B[k=s*32+(l>>4)*8+j][col=t*16+(l&15)].
// This is exactly the 16x16x32 MFMA B-operand fragment order -> gemm does
// 16B LDS reads at lane*16 with zero shuffling.
__global__ __launch_bounds__(256) void convert_weight(const float* __restrict__ w,
                                                      ushort* __restrict__ img) {
    const int g = blockIdx.x * 256 + threadIdx.x;  // 0..16383
    const int j = g & 7, l = (g >> 3) & 63, ts = g >> 9;  // ts = t*8+s
    const int s = ts & 7, t = ts >> 3;
    const int k = s * 32 + (l >> 4) * 8 + j;
    const int c = t * 16 + (l & 15);
    const float v = w[k * OUT_DIM + c];
    const unsigned b = __float_as_uint(v);
    const float r = v - __uint_as_float(b & 0xFFFF0000u);  // residual after hi-truncation
    img[(ts * 2 + 0) * 512 + l * 8 + j] = (ushort)(b >> 16);
    img[(ts * 2 + 1) * 512 + l * 8 + j] = (ushort)(__float_as_uint(r) >> 16);
}

// ---------------- GEMM via MFMA, fp32 accuracy by bf16 hi/lo 3-term split ----------------
// Block = 256 = 4 waves; wave wv computes rows [blk*64+wv*16, +16) x all 64 cols.
// A-frag: m = lane&15, k = (lane>>4)*8+j. C/D: col = lane&15, row = (lane>>4)*4+reg.
__global__ __launch_bounds__(256) void gemm_mfma(const float* __restrict__ inputs,
                                                 const ushort* __restrict__ wimg,
                                                 float* __restrict__ x) {
    __shared__ ushort lds[32768];  // 64 KB -> 2 blocks/CU
    const int tid = threadIdx.x;

    // Stage the prebuilt 64KB image: 16 coalesced 16B copies per thread
    // (4096 chunks of 16B total). R6 BUG was i<4: only 16KB staged, 3/4 poison.
    #pragma unroll
    for (int i = 0; i < 16; ++i) {
        const int c = tid + i * 256;  // 16B-chunk index 0..4095
        *(int4*)(lds + c * 8) = *(const int4*)(wimg + c * 8);
    }
    __syncthreads();

    const int wv = tid >> 6, l = tid & 63;
    const int rbase = blockIdx.x * 64 + wv * 16;
    const int arow_idx = rbase + (l & 15);
    const int row_c = arow_idx < N_NODES ? arow_idx : N_NODES - 1;  // clamp loads; stores guarded
    const float* arow = inputs + (size_t)row_c * IN_DIM;
    const int koff = (l >> 4) * 8;

    // Load this lane's 64 A elements (fp32) and split to bf16 hi/lo fragments.
    bf16x8 ah[8], al[8];
    #pragma unroll
    for (int s = 0; s < 8; ++s) {
        const float4 p = *(const float4*)(arow + s * 32 + koff);
        const float4 q = *(const float4*)(arow + s * 32 + koff + 4);
        const float v[8] = {p.x, p.y, p.z, p.w, q.x, q.y, q.z, q.w};
        #pragma unroll
        for (int j = 0; j < 8; ++j) {
            const unsigned b = __float_as_uint(v[j]);
            const float r = v[j] - __uint_as_float(b & 0xFFFF0000u);
            ah[s][j] = (short)(b >> 16);
            al[s][j] = (short)(__float_as_uint(r) >> 16);
        }
    }

    f32x4 acc[4];
    #pragma unroll
    for (int t = 0; t < 4; ++t) acc[t] = (f32x4){0.f, 0.f, 0.f, 0.f};

    const bf16x8* b8 = (const bf16x8*)lds;
    #pragma unroll
    for (int t = 0; t < 4; ++t) {
        #pragma unroll
        for (int s = 0; s < 8; ++s) {
            const bf16x8 bh = b8[((t * 8 + s) * 2 + 0) * 64 + l];
            const bf16x8 blo = b8[((t * 8 + s) * 2 + 1) * 64 + l];
            acc[t] = __builtin_amdgcn_mfma_f32_16x16x32_bf16(ah[s], bh, acc[t], 0, 0, 0);
            acc[t] = __builtin_amdgcn_mfma_f32_16x16x32_bf16(al[s], bh, acc[t], 0, 0, 0);
            acc[t] = __builtin_amdgcn_mfma_f32_16x16x32_bf16(ah[s], blo, acc[t], 0, 0, 0);
        }
    }

    const int mbase = rbase + (l >> 4) * 4;
    #pragma unroll
    for (int reg = 0; reg < 4; ++reg) {
        const int row = mbase + reg;
        if (row < N_NODES) {
            #pragma unroll
            for (int t = 0; t < 4; ++t)
                x[(size_t)row * OUT_DIM + t * 16 + (l & 15)] = acc[t][reg];
        }
    }
}

// ---------------- CSR build step 1: histogram of rows ----------------
__global__ __launch_bounds__(256) void hist_kernel(const int* __restrict__ rows,
                                                   int* __restrict__ counts) {
    const int e = blockIdx.x * 256 + threadIdx.x;
    if (e < N_EDGES) atomicAdd(&counts[rows[e]], 1);
}

// ---------------- CSR step 2a: per-chunk totals ----------------
__global__ __launch_bounds__(256) void scan_reduce(const int* __restrict__ counts,
                                                   int* __restrict__ blocksums) {
    __shared__ int lds[256];
    const int b = blockIdx.x, t = threadIdx.x;
    const int base = b * SCAN_CHUNK + t * 8;
    int s = 0;
    #pragma unroll
    for (int i = 0; i < 8; ++i) {
        const int idx = base + i;
        s += (idx < N_NODES) ? counts[idx] : 0;
    }
    lds[t] = s; __syncthreads();
    for (int off = 128; off > 0; off >>= 1) {
        if (t < off) lds[t] += lds[t + off];
        __syncthreads();
    }
    if (t == 0) blocksums[b] = lds[0];
}

// ---------------- CSR step 2b: exclusive scan of chunk totals (1 wave) ----------------
__global__ __launch_bounds__(64) void scan_toplevel(const int* __restrict__ blocksums,
                                                    int* __restrict__ blockoffs) {
    const int t = threadIdx.x;
    const int mine = (t < NBLK) ? blocksums[t] : 0;
    int v = mine;
    #pragma unroll
    for (int d = 1; d < 64; d <<= 1) {
        const int u = __shfl_up(v, d, 64);
        if (t >= d) v += u;
    }
    if (t < NBLK) blockoffs[t] = v - mine;  // exclusive
}

// ---------------- CSR step 2c: full exclusive scan -> offsets, cursor ----------------
__global__ __launch_bounds__(256) void scan_final(const int* __restrict__ counts,
                                                  const int* __restrict__ blockoffs,
                                                  int* __restrict__ offsets,
                                                  int* __restrict__ cursor) {
    __shared__ int a[256], bbuf[256];
    const int b = blockIdx.x, t = threadIdx.x;
    const int base = b * SCAN_CHUNK + t * 8;
    int v[8]; int s = 0;
    #pragma unroll
    for (int i = 0; i < 8; ++i) {
        const int idx = base + i;
        v[i] = (idx < N_NODES) ? counts[idx] : 0;
        s += v[i];
    }
    a[t] = s; __syncthreads();
    int* src = a; int* dst = bbuf;
    for (int off = 1; off < 256; off <<= 1) {
        const int x = src[t] + ((t >= off) ? src[t - off] : 0);
        dst[t] = x; __syncthreads();
        int* tmp = src; src = dst; dst = tmp;
    }
    int run = blockoffs[b] + (src[t] - s);
    #pragma unroll
    for (int i = 0; i < 8; ++i) {
        const int idx = base + i;
        if (idx <= N_NODES) {
            offsets[idx] = run;
            if (idx < N_NODES) cursor[idx] = run;
        }
        run += v[i];
    }
}

// ---------------- CSR step 3: XCD-partitioned permute ----------------
__global__ __launch_bounds__(256) void permute_kernel(const int* __restrict__ rows,
                                                      const int* __restrict__ cols,
                                                      int* __restrict__ cursor,
                                                      int* __restrict__ sorted_cols) {
    const int part = blockIdx.x & (NPART - 1);
    const int e = (blockIdx.x >> 3) * 256 + threadIdx.x;
    if (e >= N_EDGES) return;
    const int r = rows[e];
    if ((unsigned)(r - part * PART_SIZE) < (unsigned)PART_SIZE) {
        const int pos = atomicAdd(&cursor[r], 1);
        sorted_cols[pos] = cols[e];
    }
}

// ---------------- Pull-mode aggregate + fused sigmoid ----------------
__global__ __launch_bounds__(256) void aggregate_kernel(const int* __restrict__ offsets,
                                                        const int* __restrict__ sorted_cols,
                                                        const float* __restrict__ x,
                                                        float* __restrict__ out) {
    const int row = blockIdx.x * 4 + (threadIdx.x >> 6);
    const int lane = threadIdx.x & 63;
    if (row >= N_NODES) return;
    const int start = offsets[row];
    const int end = offsets[row + 1];
    float acc = 0.f;
    int j = start;
    for (; j + 3 < end; j += 4) {
        const int c0 = sorted_cols[j + 0];
        const int c1 = sorted_cols[j + 1];
        const int c2 = sorted_cols[j + 2];
        const int c3 = sorted_cols[j + 3];
        const float a0 = x[(size_t)c0 * OUT_DIM + lane];
        const float a1 = x[(size_t)c1 * OUT_DIM + lane];
        const float a2 = x[(size_t)c2 * OUT_DIM + lane];
        const float a3 = x[(size_t)c3 * OUT_DIM + lane];
        acc += (a0 + a1) + (a2 + a3);
    }
    for (; j < end; ++j)
        acc += x[(size_t)sorted_cols[j] * OUT_DIM + lane];
    out[(size_t)row * OUT_DIM + lane] = 1.f / (1.f + __expf(-acc));
}

extern "C" void kernel_launch(void* const* d_in, const int* in_sizes, int n_in,
                              void* d_out, int out_size, void* d_ws, size_t ws_size,
                              hipStream_t stream) {
    const float* inputs = (const float*)d_in[0];
    const int* edge_index = (const int*)d_in[1];  // [2, N_EDGES], int32 on device
    const float* weight = (const float*)d_in[2];
    float* out = (float*)d_out;

    char* ws = (char*)d_ws;
    float* x         = (float*)(ws + X_OFF);
    int* counts      = (int*)(ws + COUNTS_OFF);
    int* offsets     = (int*)(ws + OFFSETS_OFF);
    int* cursor      = (int*)(ws + CURSOR_OFF);
    ushort* wimg     = (ushort*)(ws + CURSOR_OFF);  // 64KB alias; dead before scan_final
    int* blocksums   = (int*)(ws + BLOCKSUMS_OFF);
    int* blockoffs   = (int*)(ws + BLOCKOFFS_OFF);
    int* sorted_cols = (int*)(ws + SORTED_OFF);

    const int* rows = edge_index;
    const int* cols = edge_index + N_EDGES;

    hipMemsetAsync(counts, 0, N_NODES * sizeof(int), stream);

    convert_weight<<<64, 256, 0, stream>>>(weight, wimg);
    gemm_mfma<<<(N_NODES + 63) / 64, 256, 0, stream>>>(inputs, wimg, x);

    hist_kernel<<<(N_EDGES + 255) / 256, 256, 0, stream>>>(rows, counts);
    scan_reduce<<<NBLK, 256, 0, stream>>>(counts, blocksums);
    scan_toplevel<<<1, 64, 0, stream>>>(blocksums, blockoffs);
    scan_final<<<NBLK, 256, 0, stream>>>(counts, blockoffs, offsets, cursor);

    const int nchunks = (N_EDGES + 255) / 256;
    permute_kernel<<<nchunks * NPART, 256, 0, stream>>>(rows, cols, cursor, sorted_cols);

    aggregate_kernel<<<(N_NODES + 3) / 4, 256, 0, stream>>>(offsets, sorted_cols, x, out);
}

// Round 8
// 379.236 us; speedup vs baseline: 4.1729x; 1.0159x over previous
//
#include <hip/hip_runtime.h>
#include <hip/hip_fp16.h>
#include <math.h>

#define N_NODES 100000
#define N_EDGES 1600000
#define IN_DIM 256
#define OUT_DIM 64

#define SCAN_CHUNK 2048
#define NBLK ((N_NODES + 1 + SCAN_CHUNK - 1) / SCAN_CHUNK)  // 49

#define NPART 8
#define PART_SIZE ((N_NODES + NPART - 1) / NPART)  // 12500 rows per partition

// ---- workspace layout (bytes) ----
#define X_OFF         0UL          // 12,800,000 B used: x[N_NODES][64] fp16 (region reserves 25.6MB)
#define COUNTS_OFF    25600000UL   // 400,000 B: int counts[N_NODES]
#define OFFSETS_OFF   26000000UL   // 400,004 B: int offsets[N_NODES+1]
#define CURSOR_OFF    26400016UL   // 400,000 B: int cursor[N_NODES]; first 64KB doubles as W-image (stream-ordered: gemm reads it before scan_final writes cursor)
#define BLOCKSUMS_OFF 26800016UL   // 256 B
#define BLOCKOFFS_OFF 26800272UL   // 256 B
#define SORTED_OFF    26800544UL   // 6,400,000 B: int sorted_cols[N_EDGES]
// total ~33.2 MB

typedef short bf16x8 __attribute__((ext_vector_type(8)));
typedef float f32x4 __attribute__((ext_vector_type(4)));

// ---------------- Weight -> bf16 hi/lo B-fragment image (64 KB) ----------------
// Image layout: 64 chunks of 1KB. Chunk c=(t*8+s)*2+h, h=0:hi, 1:lo.
// Within a chunk: lane l's 16B at l*16 = 8 bf16: B[k=s*32+(l>>4)*8+j][col=t*16+(l&15)].
__global__ __launch_bounds__(256) void convert_weight(const float* __restrict__ w,
                                                      ushort* __restrict__ img) {
    const int g = blockIdx.x * 256 + threadIdx.x;  // 0..16383
    const int j = g & 7, l = (g >> 3) & 63, ts = g >> 9;  // ts = t*8+s
    const int s = ts & 7, t = ts >> 3;
    const int k = s * 32 + (l >> 4) * 8 + j;
    const int c = t * 16 + (l & 15);
    const float v = w[k * OUT_DIM + c];
    const unsigned b = __float_as_uint(v);
    const float r = v - __uint_as_float(b & 0xFFFF0000u);  // residual after hi-truncation
    img[(ts * 2 + 0) * 512 + l * 8 + j] = (ushort)(b >> 16);
    img[(ts * 2 + 1) * 512 + l * 8 + j] = (ushort)(__float_as_uint(r) >> 16);
}

// ---------------- GEMM via MFMA, fp32 accuracy by bf16 hi/lo 3-term split ----------------
// Block = 256 = 4 waves; wave wv computes rows [blk*64+wv*16, +16) x all 64 cols.
// A-frag: m = lane&15, k = (lane>>4)*8+j. C/D: col = lane&15, row = (lane>>4)*4+reg.
// Epilogue stores x as fp16 (halves the aggregate gather footprint).
__global__ __launch_bounds__(256) void gemm_mfma(const float* __restrict__ inputs,
                                                 const ushort* __restrict__ wimg,
                                                 __half* __restrict__ x) {
    __shared__ ushort lds[32768];  // 64 KB -> 2 blocks/CU
    const int tid = threadIdx.x;

    // Stage the prebuilt 64KB image: 16 coalesced 16B copies per thread.
    #pragma unroll
    for (int i = 0; i < 16; ++i) {
        const int c = tid + i * 256;  // 16B-chunk index 0..4095
        *(int4*)(lds + c * 8) = *(const int4*)(wimg + c * 8);
    }
    __syncthreads();

    const int wv = tid >> 6, l = tid & 63;
    const int rbase = blockIdx.x * 64 + wv * 16;
    const int arow_idx = rbase + (l & 15);
    const int row_c = arow_idx < N_NODES ? arow_idx : N_NODES - 1;  // clamp loads; stores guarded
    const float* arow = inputs + (size_t)row_c * IN_DIM;
    const int koff = (l >> 4) * 8;

    bf16x8 ah[8], al[8];
    #pragma unroll
    for (int s = 0; s < 8; ++s) {
        const float4 p = *(const float4*)(arow + s * 32 + koff);
        const float4 q = *(const float4*)(arow + s * 32 + koff + 4);
        const float v[8] = {p.x, p.y, p.z, p.w, q.x, q.y, q.z, q.w};
        #pragma unroll
        for (int j = 0; j < 8; ++j) {
            const unsigned b = __float_as_uint(v[j]);
            const float r = v[j] - __uint_as_float(b & 0xFFFF0000u);
            ah[s][j] = (short)(b >> 16);
            al[s][j] = (short)(__float_as_uint(r) >> 16);
        }
    }

    f32x4 acc[4];
    #pragma unroll
    for (int t = 0; t < 4; ++t) acc[t] = (f32x4){0.f, 0.f, 0.f, 0.f};

    const bf16x8* b8 = (const bf16x8*)lds;
    #pragma unroll
    for (int t = 0; t < 4; ++t) {
        #pragma unroll
        for (int s = 0; s < 8; ++s) {
            const bf16x8 bh = b8[((t * 8 + s) * 2 + 0) * 64 + l];
            const bf16x8 blo = b8[((t * 8 + s) * 2 + 1) * 64 + l];
            acc[t] = __builtin_amdgcn_mfma_f32_16x16x32_bf16(ah[s], bh, acc[t], 0, 0, 0);
            acc[t] = __builtin_amdgcn_mfma_f32_16x16x32_bf16(al[s], bh, acc[t], 0, 0, 0);
            acc[t] = __builtin_amdgcn_mfma_f32_16x16x32_bf16(ah[s], blo, acc[t], 0, 0, 0);
        }
    }

    const int mbase = rbase + (l >> 4) * 4;
    #pragma unroll
    for (int reg = 0; reg < 4; ++reg) {
        const int row = mbase + reg;
        if (row < N_NODES) {
            #pragma unroll
            for (int t = 0; t < 4; ++t)
                x[(size_t)row * OUT_DIM + t * 16 + (l & 15)] = __float2half(acc[t][reg]);
        }
    }
}

// ---------------- CSR build step 1: histogram of rows ----------------
__global__ __launch_bounds__(256) void hist_kernel(const int* __restrict__ rows,
                                                   int* __restrict__ counts) {
    const int e = blockIdx.x * 256 + threadIdx.x;
    if (e < N_EDGES) atomicAdd(&counts[rows[e]], 1);
}

// ---------------- CSR step 2a: per-chunk totals ----------------
__global__ __launch_bounds__(256) void scan_reduce(const int* __restrict__ counts,
                                                   int* __restrict__ blocksums) {
    __shared__ int lds[256];
    const int b = blockIdx.x, t = threadIdx.x;
    const int base = b * SCAN_CHUNK + t * 8;
    int s = 0;
    #pragma unroll
    for (int i = 0; i < 8; ++i) {
        const int idx = base + i;
        s += (idx < N_NODES) ? counts[idx] : 0;
    }
    lds[t] = s; __syncthreads();
    for (int off = 128; off > 0; off >>= 1) {
        if (t < off) lds[t] += lds[t + off];
        __syncthreads();
    }
    if (t == 0) blocksums[b] = lds[0];
}

// ---------------- CSR step 2b: exclusive scan of chunk totals (1 wave) ----------------
__global__ __launch_bounds__(64) void scan_toplevel(const int* __restrict__ blocksums,
                                                    int* __restrict__ blockoffs) {
    const int t = threadIdx.x;
    const int mine = (t < NBLK) ? blocksums[t] : 0;
    int v = mine;
    #pragma unroll
    for (int d = 1; d < 64; d <<= 1) {
        const int u = __shfl_up(v, d, 64);
        if (t >= d) v += u;
    }
    if (t < NBLK) blockoffs[t] = v - mine;  // exclusive
}

// ---------------- CSR step 2c: full exclusive scan -> offsets, cursor ----------------
__global__ __launch_bounds__(256) void scan_final(const int* __restrict__ counts,
                                                  const int* __restrict__ blockoffs,
                                                  int* __restrict__ offsets,
                                                  int* __restrict__ cursor) {
    __shared__ int a[256], bbuf[256];
    const int b = blockIdx.x, t = threadIdx.x;
    const int base = b * SCAN_CHUNK + t * 8;
    int v[8]; int s = 0;
    #pragma unroll
    for (int i = 0; i < 8; ++i) {
        const int idx = base + i;
        v[i] = (idx < N_NODES) ? counts[idx] : 0;
        s += v[i];
    }
    a[t] = s; __syncthreads();
    int* src = a; int* dst = bbuf;
    for (int off = 1; off < 256; off <<= 1) {
        const int x = src[t] + ((t >= off) ? src[t - off] : 0);
        dst[t] = x; __syncthreads();
        int* tmp = src; src = dst; dst = tmp;
    }
    int run = blockoffs[b] + (src[t] - s);
    #pragma unroll
    for (int i = 0; i < 8; ++i) {
        const int idx = base + i;
        if (idx <= N_NODES) {
            offsets[idx] = run;
            if (idx < N_NODES) cursor[idx] = run;
        }
        run += v[i];
    }
}

// ---------------- CSR step 3: XCD-partitioned permute ----------------
__global__ __launch_bounds__(256) void permute_kernel(const int* __restrict__ rows,
                                                      const int* __restrict__ cols,
                                                      int* __restrict__ cursor,
                                                      int* __restrict__ sorted_cols) {
    const int part = blockIdx.x & (NPART - 1);
    const int e = (blockIdx.x >> 3) * 256 + threadIdx.x;
    if (e >= N_EDGES) return;
    const int r = rows[e];
    if ((unsigned)(r - part * PART_SIZE) < (unsigned)PART_SIZE) {
        const int pos = atomicAdd(&cursor[r], 1);
        sorted_cols[pos] = cols[e];
    }
}

// ---------------- Pull-mode aggregate (fp16 gather) + fused sigmoid ----------------
// One wave per row; lane = output column. Unroll 8 for memory-level parallelism.
__global__ __launch_bounds__(256) void aggregate_kernel(const int* __restrict__ offsets,
                                                        const int* __restrict__ sorted_cols,
                                                        const __half* __restrict__ x,
                                                        float* __restrict__ out) {
    const int row = blockIdx.x * 4 + (threadIdx.x >> 6);
    const int lane = threadIdx.x & 63;
    if (row >= N_NODES) return;
    const int start = offsets[row];
    const int end = offsets[row + 1];
    float acc = 0.f;
    int j = start;
    for (; j + 7 < end; j += 8) {
        int c[8];
        #pragma unroll
        for (int u = 0; u < 8; ++u) c[u] = sorted_cols[j + u];
        float a[8];
        #pragma unroll
        for (int u = 0; u < 8; ++u) a[u] = __half2float(x[(size_t)c[u] * OUT_DIM + lane]);
        acc += ((a[0] + a[1]) + (a[2] + a[3])) + ((a[4] + a[5]) + (a[6] + a[7]));
    }
    for (; j < end; ++j)
        acc += __half2float(x[(size_t)sorted_cols[j] * OUT_DIM + lane]);
    out[(size_t)row * OUT_DIM + lane] = 1.f / (1.f + __expf(-acc));
}

extern "C" void kernel_launch(void* const* d_in, const int* in_sizes, int n_in,
                              void* d_out, int out_size, void* d_ws, size_t ws_size,
                              hipStream_t stream) {
    const float* inputs = (const float*)d_in[0];
    const int* edge_index = (const int*)d_in[1];  // [2, N_EDGES], int32 on device
    const float* weight = (const float*)d_in[2];
    float* out = (float*)d_out;

    char* ws = (char*)d_ws;
    __half* x        = (__half*)(ws + X_OFF);
    int* counts      = (int*)(ws + COUNTS_OFF);
    int* offsets     = (int*)(ws + OFFSETS_OFF);
    int* cursor      = (int*)(ws + CURSOR_OFF);
    ushort* wimg     = (ushort*)(ws + CURSOR_OFF);  // 64KB alias; dead before scan_final
    int* blocksums   = (int*)(ws + BLOCKSUMS_OFF);
    int* blockoffs   = (int*)(ws + BLOCKOFFS_OFF);
    int* sorted_cols = (int*)(ws + SORTED_OFF);

    const int* rows = edge_index;
    const int* cols = edge_index + N_EDGES;

    hipMemsetAsync(counts, 0, N_NODES * sizeof(int), stream);

    convert_weight<<<64, 256, 0, stream>>>(weight, wimg);
    gemm_mfma<<<(N_NODES + 63) / 64, 256, 0, stream>>>(inputs, wimg, x);

    hist_kernel<<<(N_EDGES + 255) / 256, 256, 0, stream>>>(rows, counts);
    scan_reduce<<<NBLK, 256, 0, stream>>>(counts, blocksums);
    scan_toplevel<<<1, 64, 0, stream>>>(blocksums, blockoffs);
    scan_final<<<NBLK, 256, 0, stream>>>(counts, blockoffs, offsets, cursor);

    const int nchunks = (N_EDGES + 255) / 256;
    permute_kernel<<<nchunks * NPART, 256, 0, stream>>>(rows, cols, cursor, sorted_cols);

    aggregate_kernel<<<(N_NODES + 3) / 4, 256, 0, stream>>>(offsets, sorted_cols, x, out);
}